// Round 16
// baseline (248.208 us; speedup 1.0000x reference)
//
#include <hip/hip_runtime.h>
#include <hip/hip_bf16.h>

// ---------------- problem constants ----------------
#define B_   2
#define S_   2048
#define D_   2048
#define H_   32
#define KV_  8
#define HD_  64
#define TOK_ (B_*S_)   // 4096
#define NQKV_ 3072     // 2048 q + 512 k + 512 v

#define RLOG 0.1803368801111179f   // 0.125 * log2(e); folded into q at RoPE time

typedef __attribute__((ext_vector_type(8))) short short8;
typedef __attribute__((ext_vector_type(4))) float f32x4;
typedef __attribute__((ext_vector_type(16))) float f32x16;

// ---------------- ws layout (bytes) ----------------
#define OFF_XB   ((size_t)0)
#define OFF_WQKV (OFF_XB   + (size_t)TOK_*D_*2)
#define OFF_WO   (OFF_WQKV + (size_t)NQKV_*D_*2)
#define OFF_QKV  (OFF_WO   + (size_t)D_*D_*2)
#define OFF_VT   (OFF_QKV  + (size_t)TOK_*NQKV_*2)
#define OFF_AO   (OFF_VT   + (size_t)B_*KV_*HD_*S_*2)
#define OFF_TAB  (OFF_AO   + (size_t)TOK_*D_*2)

__device__ __forceinline__ unsigned short f2bfu(float f) {
  unsigned int x = __float_as_uint(f);
  x += 0x7fffu + ((x >> 16) & 1u);
  return (unsigned short)(x >> 16);
}
__device__ __forceinline__ float bf2f(unsigned short u) {
  return __uint_as_float(((unsigned int)u) << 16);
}
__device__ __forceinline__ unsigned int pk2(float a, float b) {  // v_cvt_pk_bf16_f32 (verified R4)
  union { __hip_bfloat162 h; unsigned int u; } t;
  t.h = __float22bfloat162_rn(make_float2(a, b));
  return t.u;
}
__device__ __forceinline__ void gld16(const void* g, void* l) {
  __builtin_amdgcn_global_load_lds((const __attribute__((address_space(1))) void*)g,
                                   (__attribute__((address_space(3))) void*)l, 16, 0, 0);
}

// ---------------- mega prep 1: ropetab + cvtx + wtrans(Wq,Wk,Wv,Wo) in one launch ----------------
#define NB_TAB  256
#define NB_CVT  8192
#define NB_WQ   4096
#define NB_WK   1024
#define NB_WV   1024
#define NB_WO   4096
#define NB_MEGA1 (NB_TAB + NB_CVT + NB_WQ + NB_WK + NB_WV + NB_WO)
__global__ __launch_bounds__(256) void mega1_k(const float* __restrict__ x,
                                               const float* __restrict__ Wq,
                                               const float* __restrict__ Wk,
                                               const float* __restrict__ Wv,
                                               const float* __restrict__ Wo,
                                               float2* __restrict__ tab,
                                               unsigned short* __restrict__ xb,
                                               unsigned short* __restrict__ wqkvt,
                                               unsigned short* __restrict__ wot) {
  __shared__ float tile[32][33];
  int blk = blockIdx.x, tid = threadIdx.x;
  if (blk < NB_TAB) {
    int i = blk * 256 + tid;
    int s = i >> 5, j = i & 31;
    float inv = exp2f(-(float)j * (13.287712379549449f / 32.0f));
    float ang = (float)s * inv;
    tab[i] = make_float2(cosf(ang), sinf(ang));
    return;
  }
  blk -= NB_TAB;
  if (blk < NB_CVT) {
    int i = blk * 256 + tid;
    float4 f = ((const float4*)x)[i];
    ushort4 o;
    o.x = f2bfu(f.x); o.y = f2bfu(f.y); o.z = f2bfu(f.z); o.w = f2bfu(f.w);
    ((ushort4*)xb)[i] = o;
    return;
  }
  blk -= NB_CVT;
  const float* in;
  unsigned short* out;
  int gx, N;
  if (blk < NB_WQ)                { in = Wq; out = wqkvt;                         gx = 64; N = 2048; }
  else if (blk < NB_WQ + NB_WK)   { in = Wk; out = wqkvt + (size_t)2048 * 2048;   gx = 16; N = 512;  blk -= NB_WQ; }
  else if (blk < NB_WQ + NB_WK + NB_WV) { in = Wv; out = wqkvt + (size_t)2560 * 2048; gx = 16; N = 512; blk -= NB_WQ + NB_WK; }
  else                            { in = Wo; out = wot;                           gx = 64; N = 2048; blk -= NB_WQ + NB_WK + NB_WV; }
  int bx = blk % gx, by = blk / gx;
  int n0 = bx * 32, k0 = by * 32;
  int tx = tid & 31, ty = tid >> 5;            // 32 x 8
#pragma unroll
  for (int i = 0; i < 4; ++i)
    tile[ty + 8*i][tx] = in[(size_t)(k0 + ty + 8*i) * N + n0 + tx];
  __syncthreads();
#pragma unroll
  for (int i = 0; i < 4; ++i)
    out[(size_t)(n0 + ty + 8*i) * 2048 + k0 + tx] = f2bfu(tile[tx][ty + 8*i]);
}

// ---------------- mega prep 2: rope (q,k in-place; q scaled RLOG) + vtrans kappa ----------------
#define NB_ROPE 20480
#define NB_VT   2048
#define NB_MEGA2 (NB_ROPE + NB_VT)
__global__ __launch_bounds__(256) void mega2_k(unsigned short* __restrict__ qkv,
                                               const float2* __restrict__ tab,
                                               unsigned short* __restrict__ vt) {
  __shared__ unsigned short tileu[32][33];
  int blk = blockIdx.x, tid = threadIdx.x;
  if (blk < NB_ROPE) {
    int idx = blk * 256 + tid;
    int tok = idx / 1280, r = idx % 1280;
    int col, j;
    float sc;
    if (r < 1024) { j = r & 31; col = (r >> 5) * 64 + j; sc = RLOG; }
    else { int rr = r - 1024; j = rr & 31; col = 2048 + (rr >> 5) * 64 + j; sc = 1.0f; }
    int s = tok & (S_ - 1);
    float2 cs = tab[s * 32 + j];
    unsigned short* p = qkv + (size_t)tok * NQKV_ + col;
    float a = bf2f(p[0]), b = bf2f(p[32]);
    p[0]  = f2bfu((a * cs.x - b * cs.y) * sc);
    p[32] = f2bfu((b * cs.x + a * cs.y) * sc);
    return;
  }
  blk -= NB_ROPE;
  // vtrans with kappa key-order (swap bits 2<->3 of key index within 16-key window):
  // attn PV B-frag (single b128 at slot (2kk+hf)^swk) then delivers keys 16kk+kappa(m,hf)
  // matching P in register order (R9/R10-verified).
  int bx = blk & 63, by = blk >> 6;            // grid 64 x 32
  int s0 = bx * 32;
  int y0 = by * 32;
  int bkv = y0 >> 6, d0 = y0 & 63;
  int b = bkv >> 3, kv = bkv & 7;
  int tx = tid & 31, ty = tid >> 5;
#pragma unroll
  for (int i = 0; i < 4; ++i)
    tileu[ty + 8*i][tx] = qkv[(size_t)(b * S_ + s0 + ty + 8*i) * NQKV_ + 2560 + kv * 64 + d0 + tx];
  __syncthreads();
  int ptx = (tx & 0x10) | (tx & 3) | ((tx & 4) << 1) | ((tx & 8) >> 1);  // swap bits 2<->3
#pragma unroll
  for (int i = 0; i < 4; ++i)
    vt[(size_t)(y0 + ty + 8*i) * (size_t)S_ + s0 + ptx] = tileu[tx][ty + 8*i];
}

// ---------------- GEMM (R10-exact) ----------------
template<int OUTF32>
__global__ __launch_bounds__(256) void gemm_bt(const unsigned short* __restrict__ A,
                                               const unsigned short* __restrict__ Bt,
                                               void* __restrict__ Cout, int M, int N, int K) {
  __shared__ unsigned short Al[2][128][32];
  __shared__ unsigned short Bl[2][128][32];
  int tid = threadIdx.x, lane = tid & 63, w = tid >> 6;
  int lr = lane & 15, lg = lane >> 4;
  int wr = w >> 1, wc = w & 1;
  int m0 = blockIdx.y * 128, n0 = blockIdx.x * 128;
  int trow = tid >> 2, tseg = tid & 3;

  auto stage = [&](int buf, int kt) {
    gld16(A + (size_t)(m0 + trow) * K + kt * 32 + tseg * 8, &Al[buf][trow][tseg * 8]);
    gld16(A + (size_t)(m0 + 64 + trow) * K + kt * 32 + tseg * 8, &Al[buf][64 + trow][tseg * 8]);
    gld16(Bt + (size_t)(n0 + trow) * K + kt * 32 + tseg * 8, &Bl[buf][trow][tseg * 8]);
    gld16(Bt + (size_t)(n0 + 64 + trow) * K + kt * 32 + tseg * 8, &Bl[buf][64 + trow][tseg * 8]);
  };

  f32x4 zero4 = {0.f, 0.f, 0.f, 0.f};
  f32x4 acc[4][4];
#pragma unroll
  for (int mi = 0; mi < 4; ++mi)
#pragma unroll
    for (int ni = 0; ni < 4; ++ni) acc[mi][ni] = zero4;

  int nk = K >> 5;
  stage(0, 0);
  int buf = 0;
  for (int kt = 0; kt < nk; ++kt) {
    __syncthreads();
    if (kt + 1 < nk) stage(buf ^ 1, kt + 1);
    short8 af[4], bfr[4];
#pragma unroll
    for (int i = 0; i < 4; ++i) {
      af[i]  = *(const short8*)&Al[buf][64 * wr + 16 * i + lr][lg * 8];
      bfr[i] = *(const short8*)&Bl[buf][64 * wc + 16 * i + lr][lg * 8];
    }
#pragma unroll
    for (int mi = 0; mi < 4; ++mi)
#pragma unroll
      for (int ni = 0; ni < 4; ++ni)
        acc[mi][ni] = __builtin_amdgcn_mfma_f32_16x16x32_bf16(af[mi], bfr[ni], acc[mi][ni], 0, 0, 0);
    buf ^= 1;
  }
#pragma unroll
  for (int mi = 0; mi < 4; ++mi)
#pragma unroll
    for (int ni = 0; ni < 4; ++ni)
#pragma unroll
      for (int r = 0; r < 4; ++r) {
        int row = m0 + 64 * wr + 16 * mi + lg * 4 + r;
        int col = n0 + 64 * wc + 16 * ni + lr;
        float v = acc[mi][ni][r];
        if (OUTF32) ((float*)Cout)[(size_t)row * N + col] = v;
        else ((unsigned short*)Cout)[(size_t)row * N + col] = f2bfu(v);
      }
}

// ---------------- flash attention: KVBLK=128, contiguity-correct staging ----------------
// grid 512 (64 bh x 8 qt), 8 waves x 32 q-rows. ONE barrier interval per 128-key tile.
// gld16 rule (m104): LDS dest must be wave-uniform base + lane*16 -> every shot maps
// lane l to slot l&(slots/row-1), row l>>log2(slots/row), with row stride = slots*16B.
// K LDS [128 keys][64 d] (8 slots/row): shot = 64 rows; 2 shots.
// V^T LDS [64 d][128 keys kappa-order] (16 slots/row): shot = 32 rows; 2 shots.
// Swizzle: slot j holds global col (j&8)|((j&7)^(row&7)) (3-bit XOR, bit 3 preserved).
__global__ __launch_bounds__(512) void attn_k(const unsigned short* __restrict__ qkv,
                                              const unsigned short* __restrict__ vt,
                                              unsigned short* __restrict__ ao) {
  __shared__ unsigned short Kl[2][128][64];
  __shared__ unsigned short Vl[2][64][128];
  int wgid = blockIdx.x;                     // 0..511
  int xcd = wgid & 7, i = wgid >> 3;         // i 0..63
  int bh = xcd * 8 + (i & 7);                // 8 consecutive bh per XCD -> 1MB KV, L2-resident
  int qt = i >> 3;                           // 0..7
  int b = bh >> 5, h = bh & 31, kvh = h >> 2;
  int q0 = qt * 256;
  int tid = threadIdx.x, w = tid >> 6, lane = tid & 63;
  int lq = lane & 31, hf = lane >> 5;
  int swk = lq & 7;

  // Q fragments (pre-scaled by RLOG in rope): B-operand, col=q=lane&31
  const unsigned short* qp = qkv + (size_t)(b * S_ + q0 + w * 32 + lq) * NQKV_ + h * 64 + hf * 8;
  short8 qf[4];
#pragma unroll
  for (int k = 0; k < 4; ++k) qf[k] = *(const short8*)(qp + k * 16);

  const unsigned short* kbase = qkv + (size_t)(b * S_) * NQKV_ + 2048 + kvh * 64;
  const unsigned short* vbase = vt + (size_t)(b * KV_ + kvh) * 64 * S_;

  // K: 512 thr = 64 rows x 8 slots/shot; rows 0..63 then 64..127 ((64+r)&7 == r&7).
  int srow = tid >> 3, sslot = tid & 7;
  int kc = ((sslot ^ (srow & 7))) * 8;
  // V: 512 thr = 32 rows x 16 slots/shot; rows 0..31 then 32..63 ((32+r)&7 == r&7).
  int vrow = tid >> 4, vslot = tid & 15;
  int vc = ((vslot & 8) | ((vslot & 7) ^ (vrow & 7))) * 8;

  const unsigned short* kpg = kbase + (size_t)srow * NQKV_ + kc;
  const unsigned short* vpg = vbase + (size_t)vrow * S_ + vc;

  auto stage = [&](int buf) {
    gld16(kpg,                      &Kl[buf][srow][sslot * 8]);
    gld16(kpg + (size_t)64 * NQKV_, &Kl[buf][64 + srow][sslot * 8]);
    gld16(vpg,                      &Vl[buf][vrow][vslot * 8]);
    gld16(vpg + (size_t)32 * S_,    &Vl[buf][32 + vrow][vslot * 8]);
    kpg += (size_t)128 * NQKV_;
    vpg += 128;
  };

  f32x16 O0, O1;
#pragma unroll
  for (int r = 0; r < 16; ++r) { O0[r] = 0.f; O1[r] = 0.f; }
  float rsum = 0.f;                          // plain sum, no max tracking (q pre-scaled)

  // hb in {0,64}: key half within the 128-key tile
  auto compute = [&](int buf, int hb) {
    // --- S^T = K Q^T (log2-domain scores) ---
    f32x16 sa, sb;
#pragma unroll
    for (int r = 0; r < 16; ++r) { sa[r] = 0.f; sb[r] = 0.f; }
#pragma unroll
    for (int kst = 0; kst < 4; ++kst) {
      short8 kf = *(const short8*)&Kl[buf][hb + lq][((kst * 2 + hf) ^ swk) * 8];
      sa = __builtin_amdgcn_mfma_f32_32x32x16_bf16(kf, qf[kst], sa, 0, 0, 0);
    }
#pragma unroll
    for (int kst = 0; kst < 4; ++kst) {
      short8 kf = *(const short8*)&Kl[buf][hb + 32 + lq][((kst * 2 + hf) ^ swk) * 8];
      sb = __builtin_amdgcn_mfma_f32_32x32x16_bf16(kf, qf[kst], sb, 0, 0, 0);
    }

    // --- P = exp2(S); tree-sum (4 parallel chains) ---
    float c0 = 0.f, c1 = 0.f, c2 = 0.f, c3 = 0.f;
#pragma unroll
    for (int r = 0; r < 16; r += 4) {
      sa[r]   = exp2f(sa[r]);   c0 += sa[r];
      sa[r+1] = exp2f(sa[r+1]); c1 += sa[r+1];
      sa[r+2] = exp2f(sa[r+2]); c2 += sa[r+2];
      sa[r+3] = exp2f(sa[r+3]); c3 += sa[r+3];
    }
#pragma unroll
    for (int r = 0; r < 16; r += 4) {
      sb[r]   = exp2f(sb[r]);   c0 += sb[r];
      sb[r+1] = exp2f(sb[r+1]); c1 += sb[r+1];
      sb[r+2] = exp2f(sb[r+2]); c2 += sb[r+2];
      sb[r+3] = exp2f(sb[r+3]); c3 += sb[r+3];
    }
    float rs = (c0 + c1) + (c2 + c3);
    rs += __shfl_xor(rs, 32);
    rsum += rs;

    // --- PV: A = P in register order; B = V^T b128 (kappa order baked into vt) ---
    auto pv_sub = [&](const f32x16& sc, int kkb) {   // kkb: 16-key window base within 128
#pragma unroll
      for (int k16 = 0; k16 < 2; ++k16) {
        union { unsigned int u[4]; short8 s8; } pu;
        pu.u[0] = pk2(sc[k16 * 8 + 0], sc[k16 * 8 + 1]);
        pu.u[1] = pk2(sc[k16 * 8 + 2], sc[k16 * 8 + 3]);
        pu.u[2] = pk2(sc[k16 * 8 + 4], sc[k16 * 8 + 5]);
        pu.u[3] = pk2(sc[k16 * 8 + 6], sc[k16 * 8 + 7]);
        int kk = kkb + k16;
        short8 v0 = *(const short8*)&Vl[buf][lq][((kk * 2 + hf) ^ swk) * 8];
        O0 = __builtin_amdgcn_mfma_f32_32x32x16_bf16(pu.s8, v0, O0, 0, 0, 0);
        short8 v1 = *(const short8*)&Vl[buf][32 + lq][((kk * 2 + hf) ^ swk) * 8];
        O1 = __builtin_amdgcn_mfma_f32_32x32x16_bf16(pu.s8, v1, O1, 0, 0, 0);
      }
    };
    int wb = hb >> 4;                        // window base: 0 or 4
    pv_sub(sa, wb);
    pv_sub(sb, wb + 2);
  };

  stage(0);
  for (int it = 0; it < S_ / 128; it += 2) {
    __syncthreads();
    stage(1);                                // 128-key tile it+1 (16 tiles, even count)
    compute(0, 0);
    compute(0, 64);
    __syncthreads();
    if (it + 2 < S_ / 128) stage(0);         // tile it+2
    compute(1, 0);
    compute(1, 64);
  }

  // --- epilogue: O[q=crow][d=lq or 32+lq] / rsum -> ao[b][s][h*64+d] ---
  float inv = 1.f / rsum;
#pragma unroll
  for (int r = 0; r < 16; ++r) {
    int qr = (r & 3) + 8 * (r >> 2) + 4 * hf;
    float io = __shfl(inv, qr);
    size_t row = (size_t)(b * S_ + q0 + w * 32 + qr);
    ao[row * D_ + h * 64 + lq]      = f2bfu(O0[r] * io);
    ao[row * D_ + h * 64 + 32 + lq] = f2bfu(O1[r] * io);
  }
}

// ---------------- launch ----------------
extern "C" void kernel_launch(void* const* d_in, const int* in_sizes, int n_in,
                              void* d_out, int out_size, void* d_ws, size_t ws_size,
                              hipStream_t stream) {
  const float* x  = (const float*)d_in[0];
  const float* Wq = (const float*)d_in[1];
  const float* Wk = (const float*)d_in[2];
  const float* Wv = (const float*)d_in[3];
  const float* Wo = (const float*)d_in[4];

  char* ws = (char*)d_ws;
  unsigned short* xb    = (unsigned short*)(ws + OFF_XB);
  unsigned short* wqkvt = (unsigned short*)(ws + OFF_WQKV);
  unsigned short* wot   = (unsigned short*)(ws + OFF_WO);
  unsigned short* qkv   = (unsigned short*)(ws + OFF_QKV);
  unsigned short* vt    = (unsigned short*)(ws + OFF_VT);
  unsigned short* ao    = (unsigned short*)(ws + OFF_AO);
  float2*         tab   = (float2*)(ws + OFF_TAB);

  mega1_k<<<dim3(NB_MEGA1), dim3(256), 0, stream>>>(x, Wq, Wk, Wv, Wo, tab, xb, wqkvt, wot);
  gemm_bt<0><<<dim3(NQKV_/128, TOK_/128), dim3(256), 0, stream>>>(xb, wqkvt, (void*)qkv, TOK_, NQKV_, D_);
  mega2_k<<<dim3(NB_MEGA2), dim3(256), 0, stream>>>(qkv, tab, vt);
  attn_k<<<dim3(512), dim3(512), 0, stream>>>(qkv, vt, ao);
  gemm_bt<1><<<dim3(D_/128, TOK_/128), dim3(256), 0, stream>>>(ao, wot, d_out, TOK_, D_, D_);
}

// Round 17
// 242.945 us; speedup vs baseline: 1.0217x; 1.0217x over previous
//
#include <hip/hip_runtime.h>
#include <hip/hip_bf16.h>

// ---------------- problem constants ----------------
#define B_   2
#define S_   2048
#define D_   2048
#define H_   32
#define KV_  8
#define HD_  64
#define TOK_ (B_*S_)   // 4096
#define NQKV_ 3072     // 2048 q + 512 k + 512 v

#define RLOG 0.1803368801111179f   // 0.125 * log2(e); folded into q at RoPE time

typedef __attribute__((ext_vector_type(8))) short short8;
typedef __attribute__((ext_vector_type(4))) float f32x4;
typedef __attribute__((ext_vector_type(16))) float f32x16;

// ---------------- ws layout (bytes) ----------------
#define OFF_XB   ((size_t)0)
#define OFF_WQKV (OFF_XB   + (size_t)TOK_*D_*2)
#define OFF_WO   (OFF_WQKV + (size_t)NQKV_*D_*2)
#define OFF_QKV  (OFF_WO   + (size_t)D_*D_*2)
#define OFF_VT   (OFF_QKV  + (size_t)TOK_*NQKV_*2)
#define OFF_AO   (OFF_VT   + (size_t)B_*KV_*HD_*S_*2)
#define OFF_TAB  (OFF_AO   + (size_t)TOK_*D_*2)

__device__ __forceinline__ unsigned short f2bfu(float f) {
  unsigned int x = __float_as_uint(f);
  x += 0x7fffu + ((x >> 16) & 1u);
  return (unsigned short)(x >> 16);
}
__device__ __forceinline__ float bf2f(unsigned short u) {
  return __uint_as_float(((unsigned int)u) << 16);
}
__device__ __forceinline__ unsigned int pk2(float a, float b) {  // v_cvt_pk_bf16_f32 (verified R4)
  union { __hip_bfloat162 h; unsigned int u; } t;
  t.h = __float22bfloat162_rn(make_float2(a, b));
  return t.u;
}
__device__ __forceinline__ void gld16(const void* g, void* l) {
  __builtin_amdgcn_global_load_lds((const __attribute__((address_space(1))) void*)g,
                                   (__attribute__((address_space(3))) void*)l, 16, 0, 0);
}

// ---------------- mega prep 1: ropetab + cvtx + wtrans(Wq,Wk,Wv,Wo) in one launch ----------------
#define NB_TAB  256
#define NB_CVT  8192
#define NB_WQ   4096
#define NB_WK   1024
#define NB_WV   1024
#define NB_WO   4096
#define NB_MEGA1 (NB_TAB + NB_CVT + NB_WQ + NB_WK + NB_WV + NB_WO)
__global__ __launch_bounds__(256) void mega1_k(const float* __restrict__ x,
                                               const float* __restrict__ Wq,
                                               const float* __restrict__ Wk,
                                               const float* __restrict__ Wv,
                                               const float* __restrict__ Wo,
                                               float2* __restrict__ tab,
                                               unsigned short* __restrict__ xb,
                                               unsigned short* __restrict__ wqkvt,
                                               unsigned short* __restrict__ wot) {
  __shared__ float tile[32][33];
  int blk = blockIdx.x, tid = threadIdx.x;
  if (blk < NB_TAB) {
    int i = blk * 256 + tid;
    int s = i >> 5, j = i & 31;
    float inv = exp2f(-(float)j * (13.287712379549449f / 32.0f));
    float ang = (float)s * inv;
    tab[i] = make_float2(cosf(ang), sinf(ang));
    return;
  }
  blk -= NB_TAB;
  if (blk < NB_CVT) {
    int i = blk * 256 + tid;
    float4 f = ((const float4*)x)[i];
    ushort4 o;
    o.x = f2bfu(f.x); o.y = f2bfu(f.y); o.z = f2bfu(f.z); o.w = f2bfu(f.w);
    ((ushort4*)xb)[i] = o;
    return;
  }
  blk -= NB_CVT;
  const float* in;
  unsigned short* out;
  int gx, N;
  if (blk < NB_WQ)                { in = Wq; out = wqkvt;                         gx = 64; N = 2048; }
  else if (blk < NB_WQ + NB_WK)   { in = Wk; out = wqkvt + (size_t)2048 * 2048;   gx = 16; N = 512;  blk -= NB_WQ; }
  else if (blk < NB_WQ + NB_WK + NB_WV) { in = Wv; out = wqkvt + (size_t)2560 * 2048; gx = 16; N = 512; blk -= NB_WQ + NB_WK; }
  else                            { in = Wo; out = wot;                           gx = 64; N = 2048; blk -= NB_WQ + NB_WK + NB_WV; }
  int bx = blk % gx, by = blk / gx;
  int n0 = bx * 32, k0 = by * 32;
  int tx = tid & 31, ty = tid >> 5;            // 32 x 8
#pragma unroll
  for (int i = 0; i < 4; ++i)
    tile[ty + 8*i][tx] = in[(size_t)(k0 + ty + 8*i) * N + n0 + tx];
  __syncthreads();
#pragma unroll
  for (int i = 0; i < 4; ++i)
    out[(size_t)(n0 + ty + 8*i) * 2048 + k0 + tx] = f2bfu(tile[tx][ty + 8*i]);
}

// ---------------- mega prep 2: rope (q,k in-place; q scaled RLOG) + vtrans kappa ----------------
#define NB_ROPE 20480
#define NB_VT   2048
#define NB_MEGA2 (NB_ROPE + NB_VT)
__global__ __launch_bounds__(256) void mega2_k(unsigned short* __restrict__ qkv,
                                               const float2* __restrict__ tab,
                                               unsigned short* __restrict__ vt) {
  __shared__ unsigned short tileu[32][33];
  int blk = blockIdx.x, tid = threadIdx.x;
  if (blk < NB_ROPE) {
    int idx = blk * 256 + tid;
    int tok = idx / 1280, r = idx % 1280;
    int col, j;
    float sc;
    if (r < 1024) { j = r & 31; col = (r >> 5) * 64 + j; sc = RLOG; }
    else { int rr = r - 1024; j = rr & 31; col = 2048 + (rr >> 5) * 64 + j; sc = 1.0f; }
    int s = tok & (S_ - 1);
    float2 cs = tab[s * 32 + j];
    unsigned short* p = qkv + (size_t)tok * NQKV_ + col;
    float a = bf2f(p[0]), b = bf2f(p[32]);
    p[0]  = f2bfu((a * cs.x - b * cs.y) * sc);
    p[32] = f2bfu((b * cs.x + a * cs.y) * sc);
    return;
  }
  blk -= NB_ROPE;
  // vtrans with kappa key-order (swap bits 2<->3 of key index within 16-key window):
  // attn PV B-frag (single b128 at slot (2kk+hf)^swk) then delivers keys 16kk+kappa(m,hf)
  // matching P in register order (R9/R10-verified).
  int bx = blk & 63, by = blk >> 6;            // grid 64 x 32
  int s0 = bx * 32;
  int y0 = by * 32;
  int bkv = y0 >> 6, d0 = y0 & 63;
  int b = bkv >> 3, kv = bkv & 7;
  int tx = tid & 31, ty = tid >> 5;
#pragma unroll
  for (int i = 0; i < 4; ++i)
    tileu[ty + 8*i][tx] = qkv[(size_t)(b * S_ + s0 + ty + 8*i) * NQKV_ + 2560 + kv * 64 + d0 + tx];
  __syncthreads();
  int ptx = (tx & 0x10) | (tx & 3) | ((tx & 4) << 1) | ((tx & 8) >> 1);  // swap bits 2<->3
#pragma unroll
  for (int i = 0; i < 4; ++i)
    vt[(size_t)(y0 + ty + 8*i) * (size_t)S_ + s0 + ptx] = tileu[tx][ty + 8*i];
}

// ---------------- GEMM (R10-exact) ----------------
template<int OUTF32>
__global__ __launch_bounds__(256) void gemm_bt(const unsigned short* __restrict__ A,
                                               const unsigned short* __restrict__ Bt,
                                               void* __restrict__ Cout, int M, int N, int K) {
  __shared__ unsigned short Al[2][128][32];
  __shared__ unsigned short Bl[2][128][32];
  int tid = threadIdx.x, lane = tid & 63, w = tid >> 6;
  int lr = lane & 15, lg = lane >> 4;
  int wr = w >> 1, wc = w & 1;
  int m0 = blockIdx.y * 128, n0 = blockIdx.x * 128;
  int trow = tid >> 2, tseg = tid & 3;

  auto stage = [&](int buf, int kt) {
    gld16(A + (size_t)(m0 + trow) * K + kt * 32 + tseg * 8, &Al[buf][trow][tseg * 8]);
    gld16(A + (size_t)(m0 + 64 + trow) * K + kt * 32 + tseg * 8, &Al[buf][64 + trow][tseg * 8]);
    gld16(Bt + (size_t)(n0 + trow) * K + kt * 32 + tseg * 8, &Bl[buf][trow][tseg * 8]);
    gld16(Bt + (size_t)(n0 + 64 + trow) * K + kt * 32 + tseg * 8, &Bl[buf][64 + trow][tseg * 8]);
  };

  f32x4 zero4 = {0.f, 0.f, 0.f, 0.f};
  f32x4 acc[4][4];
#pragma unroll
  for (int mi = 0; mi < 4; ++mi)
#pragma unroll
    for (int ni = 0; ni < 4; ++ni) acc[mi][ni] = zero4;

  int nk = K >> 5;
  stage(0, 0);
  int buf = 0;
  for (int kt = 0; kt < nk; ++kt) {
    __syncthreads();
    if (kt + 1 < nk) stage(buf ^ 1, kt + 1);
    short8 af[4], bfr[4];
#pragma unroll
    for (int i = 0; i < 4; ++i) {
      af[i]  = *(const short8*)&Al[buf][64 * wr + 16 * i + lr][lg * 8];
      bfr[i] = *(const short8*)&Bl[buf][64 * wc + 16 * i + lr][lg * 8];
    }
#pragma unroll
    for (int mi = 0; mi < 4; ++mi)
#pragma unroll
      for (int ni = 0; ni < 4; ++ni)
        acc[mi][ni] = __builtin_amdgcn_mfma_f32_16x16x32_bf16(af[mi], bfr[ni], acc[mi][ni], 0, 0, 0);
    buf ^= 1;
  }
#pragma unroll
  for (int mi = 0; mi < 4; ++mi)
#pragma unroll
    for (int ni = 0; ni < 4; ++ni)
#pragma unroll
      for (int r = 0; r < 4; ++r) {
        int row = m0 + 64 * wr + 16 * mi + lg * 4 + r;
        int col = n0 + 64 * wc + 16 * ni + lr;
        float v = acc[mi][ni][r];
        if (OUTF32) ((float*)Cout)[(size_t)row * N + col] = v;
        else ((unsigned short*)Cout)[(size_t)row * N + col] = f2bfu(v);
      }
}

// ---------------- flash attention: R10 structure exactly ----------------
// grid 512 (64 bh x 8 qt), 8 waves x 32 q-rows; K/V staged once per block.
// PV: A = P packed in REGISTER ORDER (k-slot m of half hf = key 16kk+kappa(m,hf));
// B = V^T b128 at slot (2kk+hf)^swk — correct because vt stores kappa key order.
// Constraint (R9/R11/R16): any edit pushing VGPR past 64 at 512 thr costs ~10%.
__global__ __launch_bounds__(512) void attn_k(const unsigned short* __restrict__ qkv,
                                              const unsigned short* __restrict__ vt,
                                              unsigned short* __restrict__ ao) {
  __shared__ unsigned short Kl[2][64][64];   // [key][d], XOR-swizzled 16B slots
  __shared__ unsigned short Vl[2][64][64];   // V^T [d][key kappa-order], XOR-swizzled
  int wgid = blockIdx.x;                     // 0..511
  int xcd = wgid & 7, i = wgid >> 3;         // i 0..63
  int bh = xcd * 8 + (i & 7);                // 8 consecutive bh per XCD -> 1MB KV, L2-resident
  int qt = i >> 3;                           // 0..7
  int b = bh >> 5, h = bh & 31, kvh = h >> 2;
  int q0 = qt * 256;
  int tid = threadIdx.x, w = tid >> 6, lane = tid & 63;
  int lq = lane & 31, hf = lane >> 5;
  int swk = lq & 7;

  // Q fragments (pre-scaled by RLOG in rope): B-operand, col=q=lane&31
  const unsigned short* qp = qkv + (size_t)(b * S_ + q0 + w * 32 + lq) * NQKV_ + h * 64 + hf * 8;
  short8 qf[4];
#pragma unroll
  for (int k = 0; k < 4; ++k) qf[k] = *(const short8*)(qp + k * 16);

  const unsigned short* kbase = qkv + (size_t)(b * S_) * NQKV_ + 2048 + kvh * 64;
  const unsigned short* vbase = vt + (size_t)(b * KV_ + kvh) * 64 * S_;
  int srow = tid >> 3, sslot = tid & 7;      // 512 thr: 64 rows x 8 slots -> one 16B shot each
  int scol = (sslot ^ (srow & 7)) * 8;       // pre-swizzled global source column (rule 21)

  const unsigned short* kpg = kbase + (size_t)srow * NQKV_ + scol;
  const unsigned short* vpg = vbase + (size_t)srow * S_ + scol;

  auto stage = [&](int buf) {
    gld16(kpg, &Kl[buf][srow][sslot * 8]);
    gld16(vpg, &Vl[buf][srow][sslot * 8]);
    kpg += (size_t)64 * NQKV_;
    vpg += 64;
  };

  f32x16 O0, O1;
#pragma unroll
  for (int r = 0; r < 16; ++r) { O0[r] = 0.f; O1[r] = 0.f; }
  float rsum = 0.f;                          // plain sum, no max tracking (q pre-scaled)

  auto compute = [&](int buf) {
    // --- S^T = K Q^T (log2-domain scores) ---
    f32x16 sa, sb;
#pragma unroll
    for (int r = 0; r < 16; ++r) { sa[r] = 0.f; sb[r] = 0.f; }
#pragma unroll
    for (int kst = 0; kst < 4; ++kst) {
      short8 kf = *(const short8*)&Kl[buf][lq][((kst * 2 + hf) ^ swk) * 8];
      sa = __builtin_amdgcn_mfma_f32_32x32x16_bf16(kf, qf[kst], sa, 0, 0, 0);
    }
#pragma unroll
    for (int kst = 0; kst < 4; ++kst) {
      short8 kf = *(const short8*)&Kl[buf][32 + lq][((kst * 2 + hf) ^ swk) * 8];
      sb = __builtin_amdgcn_mfma_f32_32x32x16_bf16(kf, qf[kst], sb, 0, 0, 0);
    }

    // --- P = exp2(S); tree-sum (4 parallel chains) ---
    float c0 = 0.f, c1 = 0.f, c2 = 0.f, c3 = 0.f;
#pragma unroll
    for (int r = 0; r < 16; r += 4) {
      sa[r]   = exp2f(sa[r]);   c0 += sa[r];
      sa[r+1] = exp2f(sa[r+1]); c1 += sa[r+1];
      sa[r+2] = exp2f(sa[r+2]); c2 += sa[r+2];
      sa[r+3] = exp2f(sa[r+3]); c3 += sa[r+3];
    }
#pragma unroll
    for (int r = 0; r < 16; r += 4) {
      sb[r]   = exp2f(sb[r]);   c0 += sb[r];
      sb[r+1] = exp2f(sb[r+1]); c1 += sb[r+1];
      sb[r+2] = exp2f(sb[r+2]); c2 += sb[r+2];
      sb[r+3] = exp2f(sb[r+3]); c3 += sb[r+3];
    }
    float rs = (c0 + c1) + (c2 + c3);
    rs += __shfl_xor(rs, 32);
    rsum += rs;

    // --- PV: A = P in register order; B = V^T b128 (kappa order baked into vt) ---
    auto pv_sub = [&](const f32x16& sc, int kkb) {   // kkb: window base (0 for sa, 2 for sb)
#pragma unroll
      for (int k16 = 0; k16 < 2; ++k16) {
        union { unsigned int u[4]; short8 s8; } pu;
        pu.u[0] = pk2(sc[k16 * 8 + 0], sc[k16 * 8 + 1]);
        pu.u[1] = pk2(sc[k16 * 8 + 2], sc[k16 * 8 + 3]);
        pu.u[2] = pk2(sc[k16 * 8 + 4], sc[k16 * 8 + 5]);
        pu.u[3] = pk2(sc[k16 * 8 + 6], sc[k16 * 8 + 7]);
        int kk = kkb + k16;
        short8 v0 = *(const short8*)&Vl[buf][lq][((kk * 2 + hf) ^ swk) * 8];
        O0 = __builtin_amdgcn_mfma_f32_32x32x16_bf16(pu.s8, v0, O0, 0, 0, 0);
        short8 v1 = *(const short8*)&Vl[buf][32 + lq][((kk * 2 + hf) ^ swk) * 8];
        O1 = __builtin_amdgcn_mfma_f32_32x32x16_bf16(pu.s8, v1, O1, 0, 0, 0);
      }
    };
    pv_sub(sa, 0);
    pv_sub(sb, 2);
  };

  stage(0);
  for (int it = 0; it < S_ / 64; it += 2) {
    __syncthreads();
    stage(1);                                // tile it+1 (always exists: 32 tiles, even)
    compute(0);
    __syncthreads();
    if (it + 2 < S_ / 64) stage(0);          // tile it+2
    compute(1);
  }

  // --- epilogue: O[q=crow][d=lq or 32+lq] / rsum -> ao[b][s][h*64+d] ---
  float inv = 1.f / rsum;
#pragma unroll
  for (int r = 0; r < 16; ++r) {
    int qr = (r & 3) + 8 * (r >> 2) + 4 * hf;
    float io = __shfl(inv, qr);
    size_t row = (size_t)(b * S_ + q0 + w * 32 + qr);
    ao[row * D_ + h * 64 + lq]      = f2bfu(O0[r] * io);
    ao[row * D_ + h * 64 + 32 + lq] = f2bfu(O1[r] * io);
  }
}

// ---------------- launch ----------------
extern "C" void kernel_launch(void* const* d_in, const int* in_sizes, int n_in,
                              void* d_out, int out_size, void* d_ws, size_t ws_size,
                              hipStream_t stream) {
  const float* x  = (const float*)d_in[0];
  const float* Wq = (const float*)d_in[1];
  const float* Wk = (const float*)d_in[2];
  const float* Wv = (const float*)d_in[3];
  const float* Wo = (const float*)d_in[4];

  char* ws = (char*)d_ws;
  unsigned short* xb    = (unsigned short*)(ws + OFF_XB);
  unsigned short* wqkvt = (unsigned short*)(ws + OFF_WQKV);
  unsigned short* wot   = (unsigned short*)(ws + OFF_WO);
  unsigned short* qkv   = (unsigned short*)(ws + OFF_QKV);
  unsigned short* vt    = (unsigned short*)(ws + OFF_VT);
  unsigned short* ao    = (unsigned short*)(ws + OFF_AO);
  float2*         tab   = (float2*)(ws + OFF_TAB);

  mega1_k<<<dim3(NB_MEGA1), dim3(256), 0, stream>>>(x, Wq, Wk, Wv, Wo, tab, xb, wqkvt, wot);
  gemm_bt<0><<<dim3(NQKV_/128, TOK_/128), dim3(256), 0, stream>>>(xb, wqkvt, (void*)qkv, TOK_, NQKV_, D_);
  mega2_k<<<dim3(NB_MEGA2), dim3(256), 0, stream>>>(qkv, tab, vt);
  attn_k<<<dim3(512), dim3(512), 0, stream>>>(qkv, vt, ao);
  gemm_bt<1><<<dim3(D_/128, TOK_/128), dim3(256), 0, stream>>>(ao, wot, d_out, TOK_, D_, D_);
}